// Round 1
// baseline (144.212 us; speedup 1.0000x reference)
//
#include <hip/hip_runtime.h>
#include <hip/hip_bf16.h>

typedef _Float16 f16;
typedef _Float16 f16x2 __attribute__((ext_vector_type(2)));
typedef _Float16 f16x4 __attribute__((ext_vector_type(4)));
typedef _Float16 f16x8 __attribute__((ext_vector_type(8)));
typedef float f32x4 __attribute__((ext_vector_type(4)));

// Problem constants
#define NHEADS 6
#define NTOK 256      // tokens per window
#define NWINS 256     // windows (b_)
#define DIM 192
#define HD 32
#define C3 576        // 3*DIM
#define SCALE 0.17677669529663687f  // 1/sqrt(32)

// ---------------------------------------------------------------------------
// Kernel 1: CB[mg][h][q][k] = rpb_table[rpi[q,k], h] + mask[mg][q][k]  (f16)
// total elems = 16 * 6 * 256 * 256 = 6,291,456 ; grid 24576 x 256 exact
// ---------------------------------------------------------------------------
__global__ __launch_bounds__(256) void prep_cb_kernel(const int* __restrict__ rpi,
                                                      const float* __restrict__ mask,
                                                      const float* __restrict__ rpb,
                                                      f16* __restrict__ cb) {
  int idx = blockIdx.x * 256 + threadIdx.x;
  int k = idx & 255;
  int q = (idx >> 8) & 255;
  int t = idx >> 16;       // t = mg*6 + h
  int h = t % 6;
  int mg = t / 6;
  float v = rpb[rpi[(q << 8) | k] * 6 + h] + mask[(mg << 16) | (q << 8) | k];
  cb[idx] = (f16)v;
}

// ---------------------------------------------------------------------------
// Kernel 2: W (192x192) fp32 -> f16
// ---------------------------------------------------------------------------
__global__ __launch_bounds__(256) void prep_w_kernel(const float* __restrict__ w,
                                                     f16* __restrict__ w16) {
  int i = blockIdx.x * 256 + threadIdx.x;
  if (i < DIM * DIM) w16[i] = (f16)w[i];
}

// ---------------------------------------------------------------------------
// Kernel 3: fused window attention for one (b, h) per block.
// 256 threads = 4 waves; wave w handles q rows [64w, 64w+64) in 4 chunks of 16.
//
// S^T = K . Q^T via mfma_f32_16x16x32_f16  (M=k, N=q, K=d=32)
//   A-frag (K): lane l -> row key = kt*16 + (l&15), d = 8*(l>>4)+e (contig 8)
//   B-frag (Q^T): lane l -> col q = (l&15), d = 8*(l>>4)+e
//   C layout: col q = (l&15), row key = kt*16 + 4*(l>>4) + r
// softmax: each lane holds one q-row's keys {16kt+4g+r} -> in-lane reduce +
//   shfl_xor(16), shfl_xor(32).
// X^T = V^T . P^T via mfma_f32_16x16x16f16 (K=16): P^T's C-layout matches the
//   B-operand layout (k = 4*(l>>4)+e) exactly -> no cross-lane shuffle.
// ---------------------------------------------------------------------------
__global__ __launch_bounds__(256) void attn_kernel(const float* __restrict__ qkv,
                                                   const f16* __restrict__ cb,
                                                   f16* __restrict__ x16) {
  const int b = blockIdx.x & 255;
  const int h = blockIdx.x >> 8;
  const int tid = threadIdx.x;
  const int lane = tid & 63;
  const int wave = tid >> 6;
  const int g = lane >> 4;
  const int r16 = lane & 15;

  __shared__ f16 Klin[16 * 64 * 8];   // frag-linear: [kt][lane][8 d-elems], 16 KB
  __shared__ f16 VT[32][264];         // [d][key] padded (264) -> ~2-way conflicts

  // ---- stage K and V (thread t owns key row t) ----
  {
    const int krow = tid;
    const float* kp = qkv + (size_t)(b * NTOK + krow) * C3 + DIM + h * HD;
    float kr[32], vr[32];
#pragma unroll
    for (int i = 0; i < 8; ++i) {
      float4 t0 = ((const float4*)kp)[i];
      kr[4 * i + 0] = t0.x; kr[4 * i + 1] = t0.y; kr[4 * i + 2] = t0.z; kr[4 * i + 3] = t0.w;
      float4 t1 = ((const float4*)(kp + DIM))[i];
      vr[4 * i + 0] = t1.x; vr[4 * i + 1] = t1.y; vr[4 * i + 2] = t1.z; vr[4 * i + 3] = t1.w;
    }
#pragma unroll
    for (int gg = 0; gg < 4; ++gg) {
      f16x8 kk;
#pragma unroll
      for (int e = 0; e < 8; ++e) kk[e] = (f16)kr[gg * 8 + e];
      *((f16x8*)&Klin[(((krow >> 4) * 64) + gg * 16 + (krow & 15)) * 8]) = kk;
    }
#pragma unroll
    for (int d = 0; d < 32; ++d) VT[d][krow] = (f16)vr[d];
  }
  __syncthreads();

  const size_t cb_base = ((size_t)((b & 15) * 6 + h)) << 16;

  for (int qc = 0; qc < 4; ++qc) {
    const int qrow = wave * 64 + qc * 16 + r16;
    // Q fragment (scaled, f16)
    const float* qp = qkv + (size_t)(b * NTOK + qrow) * C3 + h * HD + g * 8;
    float4 q0 = ((const float4*)qp)[0];
    float4 q1 = ((const float4*)qp)[1];
    f16x8 qf;
    qf[0] = (f16)(q0.x * SCALE); qf[1] = (f16)(q0.y * SCALE);
    qf[2] = (f16)(q0.z * SCALE); qf[3] = (f16)(q0.w * SCALE);
    qf[4] = (f16)(q1.x * SCALE); qf[5] = (f16)(q1.y * SCALE);
    qf[6] = (f16)(q1.z * SCALE); qf[7] = (f16)(q1.w * SCALE);

    f32x4 acc[16];
#pragma unroll
    for (int kt = 0; kt < 16; ++kt) {
      acc[kt][0] = 0.f; acc[kt][1] = 0.f; acc[kt][2] = 0.f; acc[kt][3] = 0.f;
    }
#pragma unroll
    for (int kt = 0; kt < 16; ++kt) {
      f16x8 af = *((const f16x8*)&Klin[(kt * 64 + lane) * 8]);
      acc[kt] = __builtin_amdgcn_mfma_f32_16x16x32_f16(af, qf, acc[kt], 0, 0, 0);
    }

    // add bias+mask, row max
    const f16* cbp = cb + cb_base + ((size_t)qrow << 8) + g * 4;
    float m = -1e30f;
#pragma unroll
    for (int kt = 0; kt < 16; ++kt) {
      f16x4 cv = *((const f16x4*)(cbp + kt * 16));
#pragma unroll
      for (int r = 0; r < 4; ++r) {
        acc[kt][r] += (float)cv[r];
        m = fmaxf(m, acc[kt][r]);
      }
    }
    m = fmaxf(m, __shfl_xor(m, 16));
    m = fmaxf(m, __shfl_xor(m, 32));

    float s = 0.f;
#pragma unroll
    for (int kt = 0; kt < 16; ++kt) {
#pragma unroll
      for (int r = 0; r < 4; ++r) {
        float p = __expf(acc[kt][r] - m);
        acc[kt][r] = p;
        s += p;
      }
    }
    s += __shfl_xor(s, 16);
    s += __shfl_xor(s, 32);
    const float rinv = 1.0f / s;

    // PV: X^T[d][q] = sum_k V^T[d][k] * P^T[k][q]
    f32x4 xacc[2];
#pragma unroll
    for (int dt = 0; dt < 2; ++dt) {
      xacc[dt][0] = 0.f; xacc[dt][1] = 0.f; xacc[dt][2] = 0.f; xacc[dt][3] = 0.f;
    }
#pragma unroll
    for (int kt = 0; kt < 16; ++kt) {
      f16x4 pf;
      pf[0] = (f16)acc[kt][0]; pf[1] = (f16)acc[kt][1];
      pf[2] = (f16)acc[kt][2]; pf[3] = (f16)acc[kt][3];
#pragma unroll
      for (int dt = 0; dt < 2; ++dt) {
        f16x4 vf = *((const f16x4*)&VT[dt * 16 + r16][kt * 16 + g * 4]);
        xacc[dt] = __builtin_amdgcn_mfma_f32_16x16x16f16(vf, pf, xacc[dt], 0, 0, 0);
      }
    }

    // write x (f16) in [b][token][192] layout, normalized by 1/rowsum
    f16* xp = x16 + (size_t)(b * NTOK + qrow) * DIM + h * HD;
#pragma unroll
    for (int dt = 0; dt < 2; ++dt) {
      f16x2 lo, hi;
      lo[0] = (f16)(xacc[dt][0] * rinv); lo[1] = (f16)(xacc[dt][1] * rinv);
      hi[0] = (f16)(xacc[dt][2] * rinv); hi[1] = (f16)(xacc[dt][3] * rinv);
      *((f16x2*)(xp + dt * 16 + g * 4)) = lo;
      *((f16x2*)(xp + dt * 16 + g * 4 + 2)) = hi;
    }
  }
}

// ---------------------------------------------------------------------------
// Kernel 4: out[m][j] = sum_c X16[m][c] * W16[j][c] + pb[j]   (M=65536, 192x192)
// block = 4 waves, M-tile 64 (16 rows/wave), full N=192 (12 j-tiles/wave)
// ---------------------------------------------------------------------------
__global__ __launch_bounds__(256) void proj_kernel(const f16* __restrict__ x16,
                                                   const f16* __restrict__ w16,
                                                   const float* __restrict__ pb,
                                                   float* __restrict__ out) {
  const int lane = threadIdx.x & 63;
  const int wave = threadIdx.x >> 6;
  const int g = lane >> 4;
  const int r16 = lane & 15;
  const int m0 = blockIdx.x * 64 + wave * 16;

  f32x4 acc[12];
#pragma unroll
  for (int jt = 0; jt < 12; ++jt) {
    acc[jt][0] = 0.f; acc[jt][1] = 0.f; acc[jt][2] = 0.f; acc[jt][3] = 0.f;
  }
#pragma unroll
  for (int cc = 0; cc < 6; ++cc) {
    f16x8 af = *((const f16x8*)(x16 + (size_t)(m0 + r16) * DIM + cc * 32 + g * 8));
#pragma unroll
    for (int jt = 0; jt < 12; ++jt) {
      f16x8 bf = *((const f16x8*)(w16 + (size_t)(jt * 16 + r16) * DIM + cc * 32 + g * 8));
      acc[jt] = __builtin_amdgcn_mfma_f32_16x16x32_f16(af, bf, acc[jt], 0, 0, 0);
    }
  }
#pragma unroll
  for (int jt = 0; jt < 12; ++jt) {
    int j = jt * 16 + r16;
    float bias = pb[j];
#pragma unroll
    for (int r = 0; r < 4; ++r) {
      out[(size_t)(m0 + g * 4 + r) * DIM + j] = acc[jt][r] + bias;
    }
  }
}

// ---------------------------------------------------------------------------
extern "C" void kernel_launch(void* const* d_in, const int* in_sizes, int n_in,
                              void* d_out, int out_size, void* d_ws, size_t ws_size,
                              hipStream_t stream) {
  const float* qkv  = (const float*)d_in[0];
  const int*   rpi  = (const int*)d_in[1];
  const float* mask = (const float*)d_in[2];
  const float* rpb  = (const float*)d_in[3];
  const float* pw   = (const float*)d_in[4];
  const float* pbv  = (const float*)d_in[5];
  float* out = (float*)d_out;

  char* ws = (char*)d_ws;
  f16* cb  = (f16*)ws;                               // 16*6*256*256*2 = 12,582,912 B
  f16* x16 = (f16*)(ws + 12582912);                  // 256*256*192*2 = 25,165,824 B
  f16* w16 = (f16*)(ws + 12582912 + 25165824);       // 73,728 B

  prep_cb_kernel<<<24576, 256, 0, stream>>>(rpi, mask, rpb, cb);
  prep_w_kernel<<<144, 256, 0, stream>>>(pw, w16);
  attn_kernel<<<1536, 256, 0, stream>>>(qkv, cb, x16);
  proj_kernel<<<1024, 256, 0, stream>>>(x16, w16, pbv, out);
}